// Round 1
// baseline (1266.019 us; speedup 1.0000x reference)
//
#include <hip/hip_runtime.h>
#include <math.h>

#define NB    15
#define BWID  129
#define HOP   64
#define NFREQ 1025
#define EMB   128
#define MLP   512
#define OUTC  516      // BW*C*REIM
#define O2    1032
#define BATCH 2
#define TLEN  2048
#define REIM  2
#define CCH   2

#define RTOT (BATCH*NB*TLEN)   // 61440 total rows

// ---------------- LayerNorm: one wave (64 lanes) per row of 128 ----------------
__global__ __launch_bounds__(256) void ln_kernel(const float* __restrict__ q,
                                                 const float* __restrict__ gamma,
                                                 const float* __restrict__ beta,
                                                 float* __restrict__ qn)
{
    int row  = blockIdx.x * 4 + (threadIdx.x >> 6);
    int lane = threadIdx.x & 63;
    int n    = (row / TLEN) % NB;

    const float2* src = (const float2*)(q + (size_t)row * EMB);
    float2 v = src[lane];
    float s  = v.x + v.y;
    float s2 = v.x * v.x + v.y * v.y;
    #pragma unroll
    for (int off = 1; off < 64; off <<= 1) {
        s  += __shfl_xor(s,  off);
        s2 += __shfl_xor(s2, off);
    }
    float mu   = s * (1.0f / EMB);
    float var  = s2 * (1.0f / EMB) - mu * mu;
    float rstd = rsqrtf(var + 1e-5f);

    float2 g2 = ((const float2*)(gamma + n * EMB))[lane];
    float2 b2 = ((const float2*)(beta  + n * EMB))[lane];
    float2 o;
    o.x = (v.x - mu) * rstd * g2.x + b2.x;
    o.y = (v.y - mu) * rstd * g2.y + b2.y;
    ((float2*)(qn + (size_t)row * EMB))[lane] = o;
}

// ---------------- GEMM1: per band, (4096x128)@(128x512) + b1, tanh -> h ----------------
__global__ __launch_bounds__(256) void gemm1_kernel(const float* __restrict__ qn,
                                                    const float* __restrict__ W1,
                                                    const float* __restrict__ b1,
                                                    float* __restrict__ h)
{
    __shared__ float As[16][68];   // [k][m], pad 68 keeps 16B align + <=2-way banks
    __shared__ float Bs[16][64];   // [k][n]

    int n  = blockIdx.z;
    int m0 = blockIdx.y * 64;
    int n0 = blockIdx.x * 64;
    int tid = threadIdx.x;
    int b   = m0 >> 11;            // batch index (2048 rows per batch)
    int t0  = m0 & (TLEN - 1);

    const float* Abase = qn + ((size_t)(b * NB + n) * TLEN + t0) * EMB;
    const float* Bbase = W1 + (size_t)n * EMB * MLP + n0;

    int arow = tid >> 2;           // 0..63
    int ak   = (tid & 3) * 4;      // 0,4,8,12
    int brow = tid >> 4;           // 0..15
    int bcol = (tid & 15) * 4;     // 0..60
    int tx   = tid & 15, ty = tid >> 4;

    float acc[4][4] = {};

    for (int k0 = 0; k0 < EMB; k0 += 16) {
        float4 av = *(const float4*)(Abase + (size_t)arow * EMB + k0 + ak);
        float4 bv = *(const float4*)(Bbase + (size_t)(k0 + brow) * MLP + bcol);
        __syncthreads();
        As[ak + 0][arow] = av.x;
        As[ak + 1][arow] = av.y;
        As[ak + 2][arow] = av.z;
        As[ak + 3][arow] = av.w;
        *(float4*)&Bs[brow][bcol] = bv;
        __syncthreads();
        #pragma unroll
        for (int kk = 0; kk < 16; ++kk) {
            float a0 = As[kk][ty * 4 + 0];
            float a1 = As[kk][ty * 4 + 1];
            float a2 = As[kk][ty * 4 + 2];
            float a3 = As[kk][ty * 4 + 3];
            float c0 = Bs[kk][tx * 4 + 0];
            float c1 = Bs[kk][tx * 4 + 1];
            float c2 = Bs[kk][tx * 4 + 2];
            float c3 = Bs[kk][tx * 4 + 3];
            acc[0][0] += a0 * c0; acc[0][1] += a0 * c1; acc[0][2] += a0 * c2; acc[0][3] += a0 * c3;
            acc[1][0] += a1 * c0; acc[1][1] += a1 * c1; acc[1][2] += a1 * c2; acc[1][3] += a1 * c3;
            acc[2][0] += a2 * c0; acc[2][1] += a2 * c1; acc[2][2] += a2 * c2; acc[2][3] += a2 * c3;
            acc[3][0] += a3 * c0; acc[3][1] += a3 * c1; acc[3][2] += a3 * c2; acc[3][3] += a3 * c3;
        }
    }

    float4 bb = *(const float4*)(b1 + n * MLP + n0 + tx * 4);
    float* hbase = h + ((size_t)(b * NB + n) * TLEN + t0) * MLP + n0 + tx * 4;
    #pragma unroll
    for (int i = 0; i < 4; ++i) {
        int row = ty * 4 + i;
        float4 o;
        o.x = tanhf(acc[i][0] + bb.x);
        o.y = tanhf(acc[i][1] + bb.y);
        o.z = tanhf(acc[i][2] + bb.z);
        o.w = tanhf(acc[i][3] + bb.w);
        *(float4*)(hbase + (size_t)row * MLP) = o;
    }
}

// ---- GEMM2: per band, (4096x512)@(512x1032) + b2, GLU, freq-weight, scatter-add ----
// Each block computes a 64-row x 64-col tile of the "a" half AND the matching
// "g" half (cols +516), so the GLU is applied in-register and o is never stored.
__global__ __launch_bounds__(256) void gemm2_kernel(const float* __restrict__ h,
                                                    const float* __restrict__ W2,
                                                    const float* __restrict__ b2,
                                                    const float* __restrict__ fw,
                                                    float* __restrict__ masks)
{
    __shared__ float As[16][68];
    __shared__ float Ba[16][64];
    __shared__ float Bg[16][64];

    int n  = blockIdx.z;
    int m0 = blockIdx.y * 64;
    int n0 = blockIdx.x * 64;     // 9 tiles cover 516 cols (tail clamped)
    int tid = threadIdx.x;
    int b   = m0 >> 11;
    int t0  = m0 & (TLEN - 1);

    const float* Abase = h  + ((size_t)(b * NB + n) * TLEN + t0) * MLP;
    const float* W2n   = W2 + (size_t)n * MLP * O2;

    int arow = tid >> 2;
    int ak   = (tid & 3) * 4;
    int brow = tid >> 4;
    int bcol = (tid & 15) * 4;
    int tx   = tid & 15, ty = tid >> 4;

    // clamp source column so tail tile loads valid (unused) data, keeps float4 aligned
    int ca = n0 + bcol; if (ca > OUTC - 4) ca = OUTC - 4;

    float accA[4][4] = {};
    float accG[4][4] = {};

    for (int k0 = 0; k0 < MLP; k0 += 16) {
        float4 av  = *(const float4*)(Abase + (size_t)arow * MLP + k0 + ak);
        const float* wrow = W2n + (size_t)(k0 + brow) * O2;
        float4 bav = *(const float4*)(wrow + ca);
        float4 bgv = *(const float4*)(wrow + OUTC + ca);
        __syncthreads();
        As[ak + 0][arow] = av.x;
        As[ak + 1][arow] = av.y;
        As[ak + 2][arow] = av.z;
        As[ak + 3][arow] = av.w;
        *(float4*)&Ba[brow][bcol] = bav;
        *(float4*)&Bg[brow][bcol] = bgv;
        __syncthreads();
        #pragma unroll
        for (int kk = 0; kk < 16; ++kk) {
            float a0 = As[kk][ty * 4 + 0];
            float a1 = As[kk][ty * 4 + 1];
            float a2 = As[kk][ty * 4 + 2];
            float a3 = As[kk][ty * 4 + 3];
            #pragma unroll
            for (int j = 0; j < 4; ++j) {
                float wa = Ba[kk][tx * 4 + j];
                float wg = Bg[kk][tx * 4 + j];
                accA[0][j] += a0 * wa; accG[0][j] += a0 * wg;
                accA[1][j] += a1 * wa; accG[1][j] += a1 * wg;
                accA[2][j] += a2 * wa; accG[2][j] += a2 * wg;
                accA[3][j] += a3 * wa; accG[3][j] += a3 * wg;
            }
        }
    }

    #pragma unroll
    for (int j = 0; j < 4; ++j) {
        int c = n0 + tx * 4 + j;
        if (c >= OUTC) continue;
        float biasa = b2[n * O2 + c];
        float biasg = b2[n * O2 + OUTC + c];
        int cc  = c / 258;
        int rem = c % 258;
        int bw  = rem >> 1;
        int r   = rem & 1;
        float w = fw[n * BWID + bw];
        int f   = n * HOP + bw;
        size_t base = (((size_t)(b * CCH + cc) * NFREQ + f) * TLEN) * REIM + r;
        #pragma unroll
        for (int i = 0; i < 4; ++i) {
            int t = t0 + ty * 4 + i;
            float a = accA[i][j] + biasa;
            float g = accG[i][j] + biasg;
            float m = a * w / (1.0f + expf(-g));
            atomicAdd(masks + base + (size_t)t * REIM, m);
        }
    }
}

extern "C" void kernel_launch(void* const* d_in, const int* in_sizes, int n_in,
                              void* d_out, int out_size, void* d_ws, size_t ws_size,
                              hipStream_t stream) {
    const float* q     = (const float*)d_in[0];
    const float* gamma = (const float*)d_in[1];
    const float* beta  = (const float*)d_in[2];
    const float* W1    = (const float*)d_in[3];
    const float* b1    = (const float*)d_in[4];
    const float* W2    = (const float*)d_in[5];
    const float* b2    = (const float*)d_in[6];
    const float* fw    = (const float*)d_in[7];
    float* out = (float*)d_out;

    float* qn = (float*)d_ws;                       // 61440*128 f32 = 31.5 MB
    float* h  = qn + (size_t)RTOT * EMB;            // 61440*512 f32 = 125.8 MB

    hipMemsetAsync(out, 0, (size_t)out_size * sizeof(float), stream);
    ln_kernel<<<RTOT / 4, 256, 0, stream>>>(q, gamma, beta, qn);
    gemm1_kernel<<<dim3(MLP / 64, (BATCH * TLEN) / 64, NB), 256, 0, stream>>>(qn, W1, b1, h);
    gemm2_kernel<<<dim3(9, (BATCH * TLEN) / 64, NB), 256, 0, stream>>>(h, W2, b2, fw, out);
}

// Round 2
// 321.003 us; speedup vs baseline: 3.9439x; 3.9439x over previous
//
#include <hip/hip_runtime.h>
#include <math.h>

#define NB    15
#define BWID  129
#define HOP   64
#define NFREQ 1025
#define EMB   128
#define MLP   512
#define OUTC  516
#define O2    1032
#define BATCH 2
#define TLEN  2048
#define REIM  2
#define CCH   2
#define RTOT  (BATCH*NB*TLEN)

typedef _Float16 half8 __attribute__((ext_vector_type(8)));
typedef _Float16 half4 __attribute__((ext_vector_type(4)));
typedef _Float16 half2_ __attribute__((ext_vector_type(2)));
typedef float    floatx4 __attribute__((ext_vector_type(4)));

// global -> LDS direct (16B per lane). LDS dest = wave-uniform base + lane*16.
#define GLOAD_LDS(gsrc, ldst) \
  __builtin_amdgcn_global_load_lds((const __attribute__((address_space(1))) unsigned int*)(gsrc), \
                                   (__attribute__((address_space(3))) unsigned int*)(ldst), 16, 0, 0)

// ---------------- LayerNorm: one wave per row of 128, f16 out ----------------
__global__ __launch_bounds__(256) void ln_kernel(const float* __restrict__ q,
                                                 const float* __restrict__ gamma,
                                                 const float* __restrict__ beta,
                                                 _Float16* __restrict__ qn)
{
    int row  = blockIdx.x * 4 + (threadIdx.x >> 6);
    int lane = threadIdx.x & 63;
    int n    = (row / TLEN) % NB;

    const float2* src = (const float2*)(q + (size_t)row * EMB);
    float2 v = src[lane];
    float s  = v.x + v.y;
    float s2 = v.x * v.x + v.y * v.y;
    #pragma unroll
    for (int off = 1; off < 64; off <<= 1) {
        s  += __shfl_xor(s,  off);
        s2 += __shfl_xor(s2, off);
    }
    float mu   = s * (1.0f / EMB);
    float var  = s2 * (1.0f / EMB) - mu * mu;
    float rstd = rsqrtf(var + 1e-5f);

    float2 g2 = ((const float2*)(gamma + n * EMB))[lane];
    float2 b2 = ((const float2*)(beta  + n * EMB))[lane];
    half2_ o;
    o[0] = (_Float16)((v.x - mu) * rstd * g2.x + b2.x);
    o[1] = (_Float16)((v.y - mu) * rstd * g2.y + b2.y);
    ((half2_*)(qn + (size_t)row * EMB))[lane] = o;
}

// ---------------- transpose + f32->f16: src [R][C] -> dst [C][R], per band ----------------
__global__ __launch_bounds__(256) void transpose_cvt(const float* __restrict__ src,
                                                     _Float16* __restrict__ dst,
                                                     int R, int C)
{
    __shared__ float tile[32][33];
    const int band = blockIdx.z;
    src += (size_t)band * R * C;
    dst += (size_t)band * R * C;
    int tx = threadIdx.x & 31, ty = threadIdx.x >> 5;   // ty 0..7
    int c0 = blockIdx.x * 32, r0 = blockIdx.y * 32;
    int c = c0 + tx;
    if (c < C) {
        #pragma unroll
        for (int i = 0; i < 4; ++i)
            tile[ty + i * 8][tx] = src[(size_t)(r0 + ty + i * 8) * C + c];
    }
    __syncthreads();
    int r = r0 + tx;
    #pragma unroll
    for (int i = 0; i < 4; ++i) {
        int cw = c0 + ty + i * 8;
        if (cw < C) dst[(size_t)cw * R + r] = (_Float16)tile[tx][ty + i * 8];
    }
}

// ---------------- GEMM1 (MFMA f16): qn(4096x128) @ W1T^T -> tanh -> h f16 ----------------
// 128x128 tile, 4 waves, each wave 64x64 (4x4 frags of 16x16x32)
__global__ __launch_bounds__(256) void gemm1_mfma(const _Float16* __restrict__ qn,
                                                  const _Float16* __restrict__ W1T,
                                                  const float* __restrict__ b1,
                                                  _Float16* __restrict__ h)
{
    __shared__ _Float16 sA[128 * 64];
    __shared__ _Float16 sB[128 * 64];
    const int n   = blockIdx.z;
    const int m0  = blockIdx.y * 128;
    const int n0  = blockIdx.x * 128;
    const int tid = threadIdx.x;
    const int lane = tid & 63;
    const int wave = tid >> 6;
    const int wr = (wave >> 1) * 64;
    const int wc = (wave & 1) * 64;
    const int b = m0 >> 11, t0 = m0 & (TLEN - 1);

    const _Float16* Ab = qn  + ((size_t)(b * NB + n) * TLEN + t0) * EMB;
    const _Float16* Bb = W1T + ((size_t)n * MLP + n0) * EMB;

    floatx4 acc[4][4] = {};

    const int lrow = lane & 15;
    const int q16  = (lane >> 4) << 4;
    const int swz  = (lane & 7) << 4;

    for (int k0 = 0; k0 < EMB; k0 += 64) {
        #pragma unroll
        for (int i = 0; i < 4; ++i) {
            int g = tid + i * 256;
            int r = g >> 3, kb = g & 7;
            int sk = kb ^ (r & 7);
            GLOAD_LDS(Ab + (size_t)r * EMB + k0 + sk * 8, sA + g * 8);
            GLOAD_LDS(Bb + (size_t)r * EMB + k0 + sk * 8, sB + g * 8);
        }
        __syncthreads();
        #pragma unroll
        for (int kk = 0; kk < 2; ++kk) {
            half8 af[4], bf[4];
            #pragma unroll
            for (int m = 0; m < 4; ++m) {
                int r = wr + m * 16 + lrow;
                af[m] = *(const half8*)((const char*)sA + r * 128 + (((kk << 6) | q16) ^ swz));
            }
            #pragma unroll
            for (int nf = 0; nf < 4; ++nf) {
                int r = wc + nf * 16 + lrow;
                bf[nf] = *(const half8*)((const char*)sB + r * 128 + (((kk << 6) | q16) ^ swz));
            }
            #pragma unroll
            for (int m = 0; m < 4; ++m)
                #pragma unroll
                for (int nf = 0; nf < 4; ++nf)
                    acc[m][nf] = __builtin_amdgcn_mfma_f32_16x16x32_f16(af[m], bf[nf], acc[m][nf], 0, 0, 0);
        }
        __syncthreads();
    }

    const int rq = (lane >> 4) * 4;
    _Float16* hb = h + ((size_t)(b * NB + n) * TLEN + t0) * MLP;
    #pragma unroll
    for (int nf = 0; nf < 4; ++nf) {
        int col = n0 + wc + nf * 16 + lrow;
        float bias = b1[n * MLP + col];
        #pragma unroll
        for (int m = 0; m < 4; ++m) {
            int rbase = wr + m * 16 + rq;
            #pragma unroll
            for (int r = 0; r < 4; ++r) {
                float v = tanhf(acc[m][nf][r] + bias);
                hb[(size_t)(rbase + r) * MLP + col] = (_Float16)v;
            }
        }
    }
}

// ---------------- GEMM2 (MFMA f16): h(4096x512) @ W2T^T, GLU+fw -> m f16 [b][n][c][t] ----------------
// 128 rows x (64 a-cols + 64 g-cols); 4 waves: wave = 64 rows x (32a+32g)
__global__ __launch_bounds__(256) void gemm2_mfma(const _Float16* __restrict__ h,
                                                  const _Float16* __restrict__ W2T,
                                                  const float* __restrict__ b2,
                                                  const float* __restrict__ fw,
                                                  _Float16* __restrict__ mws)
{
    __shared__ _Float16 sA[128 * 64];
    __shared__ _Float16 sBa[64 * 64];
    __shared__ _Float16 sBg[64 * 64];
    const int n   = blockIdx.z;
    const int m0  = blockIdx.y * 128;
    const int n0  = blockIdx.x * 64;
    const int tid = threadIdx.x;
    const int lane = tid & 63;
    const int wave = tid >> 6;
    const int wr = (wave >> 1) * 64;
    const int wc = (wave & 1) * 32;
    const int b = m0 >> 11, t0 = m0 & (TLEN - 1);

    const _Float16* Ab  = h   + ((size_t)(b * NB + n) * TLEN + t0) * MLP;
    const _Float16* W2n = W2T + (size_t)n * O2 * MLP;

    floatx4 accA[4][2] = {};
    floatx4 accG[4][2] = {};

    const int lrow = lane & 15;
    const int q16  = (lane >> 4) << 4;
    const int swz  = (lane & 7) << 4;

    for (int k0 = 0; k0 < MLP; k0 += 64) {
        #pragma unroll
        for (int i = 0; i < 4; ++i) {
            int g = tid + i * 256;
            int r = g >> 3, kb = g & 7;
            int sk = kb ^ (r & 7);
            GLOAD_LDS(Ab + (size_t)r * MLP + k0 + sk * 8, sA + g * 8);
        }
        #pragma unroll
        for (int i = 0; i < 2; ++i) {
            int g = tid + i * 256;
            int r = g >> 3, kb = g & 7;
            int sk = kb ^ (r & 7);
            int ra = n0 + r;        if (ra > OUTC - 1) ra = OUTC - 1;
            int rg = OUTC + n0 + r; if (rg > O2 - 1)   rg = O2 - 1;
            GLOAD_LDS(W2n + (size_t)ra * MLP + k0 + sk * 8, sBa + g * 8);
            GLOAD_LDS(W2n + (size_t)rg * MLP + k0 + sk * 8, sBg + g * 8);
        }
        __syncthreads();
        #pragma unroll
        for (int kk = 0; kk < 2; ++kk) {
            half8 af[4], ba[2], bg[2];
            #pragma unroll
            for (int m = 0; m < 4; ++m) {
                int r = wr + m * 16 + lrow;
                af[m] = *(const half8*)((const char*)sA + r * 128 + (((kk << 6) | q16) ^ swz));
            }
            #pragma unroll
            for (int nf = 0; nf < 2; ++nf) {
                int r = wc + nf * 16 + lrow;
                ba[nf] = *(const half8*)((const char*)sBa + r * 128 + (((kk << 6) | q16) ^ swz));
                bg[nf] = *(const half8*)((const char*)sBg + r * 128 + (((kk << 6) | q16) ^ swz));
            }
            #pragma unroll
            for (int m = 0; m < 4; ++m)
                #pragma unroll
                for (int nf = 0; nf < 2; ++nf) {
                    accA[m][nf] = __builtin_amdgcn_mfma_f32_16x16x32_f16(af[m], ba[nf], accA[m][nf], 0, 0, 0);
                    accG[m][nf] = __builtin_amdgcn_mfma_f32_16x16x32_f16(af[m], bg[nf], accG[m][nf], 0, 0, 0);
                }
        }
        __syncthreads();
    }

    const int rq = (lane >> 4) * 4;
    const float* b2n = b2 + n * O2;
    #pragma unroll
    for (int nf = 0; nf < 2; ++nf) {
        int c = n0 + wc + nf * 16 + lrow;
        bool valid = c < OUTC;
        int cl = valid ? c : OUTC - 1;
        float biasA = b2n[cl];
        float biasG = b2n[OUTC + cl];
        int rem = cl % 258;
        float w = fw[n * BWID + (rem >> 1)];
        _Float16* mb = mws + ((size_t)((b * NB + n) * OUTC + cl)) * TLEN + t0;
        #pragma unroll
        for (int m = 0; m < 4; ++m) {
            int tb = wr + m * 16 + rq;
            half4 vals;
            #pragma unroll
            for (int r = 0; r < 4; ++r) {
                float a = accA[m][nf][r] + biasA;
                float g = accG[m][nf][r] + biasG;
                vals[r] = (_Float16)(a * w / (1.0f + expf(-g)));
            }
            if (valid) *(half4*)(mb + tb) = vals;
        }
    }
}

// ---------------- gather: masks[b][cc][f][t][r] = sum over <=3 overlapping bands ----------------
__global__ __launch_bounds__(256) void gather_masks(const _Float16* __restrict__ mws,
                                                    float* __restrict__ out)
{
    const int f  = blockIdx.x;
    const int bc = blockIdx.y;          // b*2 + cc
    const int b  = bc >> 1, cc = bc & 1;
    int nlo = (f >= 129) ? ((f - 65) >> 6) : 0;
    int nhi = f >> 6; if (nhi > 14) nhi = 14;
    float* ob = out + ((size_t)bc * NFREQ + f) * TLEN * REIM;
    #pragma unroll
    for (int i = 0; i < 4; ++i) {
        int tp = threadIdx.x + i * 256;
        int t  = tp * 2;
        float s0 = 0.f, s1 = 0.f, s2 = 0.f, s3 = 0.f;
        for (int nn = nlo; nn <= nhi; ++nn) {
            int bw = f - (nn << 6);
            int cbase = cc * 258 + (bw << 1);
            const _Float16* p = mws + ((size_t)((b * NB + nn) * OUTC + cbase)) * TLEN + t;
            s0 += (float)p[0];
            s2 += (float)p[1];
            s1 += (float)p[TLEN];
            s3 += (float)p[TLEN + 1];
        }
        *(float4*)(ob + (size_t)t * REIM) = make_float4(s0, s1, s2, s3);
    }
}

extern "C" void kernel_launch(void* const* d_in, const int* in_sizes, int n_in,
                              void* d_out, int out_size, void* d_ws, size_t ws_size,
                              hipStream_t stream) {
    const float* q     = (const float*)d_in[0];
    const float* gamma = (const float*)d_in[1];
    const float* beta  = (const float*)d_in[2];
    const float* W1    = (const float*)d_in[3];
    const float* b1    = (const float*)d_in[4];
    const float* W2    = (const float*)d_in[5];
    const float* b2    = (const float*)d_in[6];
    const float* fw    = (const float*)d_in[7];

    // ws layout (halves): h | m | qn+W1T (W2T aliases qn region after gemm1)
    _Float16* hws  = (_Float16*)d_ws;
    _Float16* mws  = hws + (size_t)RTOT * MLP;                         // 31,457,280
    _Float16* qnws = mws + (size_t)BATCH * NB * OUTC * TLEN;           // +31,703,040
    _Float16* W1T  = qnws + (size_t)RTOT * EMB;                        // +7,864,320
    _Float16* W2T  = qnws;                                             // alias (qn dead after gemm1)

    ln_kernel<<<RTOT / 4, 256, 0, stream>>>(q, gamma, beta, qnws);
    transpose_cvt<<<dim3(16, 4, NB), 256, 0, stream>>>(W1, W1T, EMB, MLP);
    gemm1_mfma<<<dim3(4, 32, NB), 256, 0, stream>>>(qnws, W1T, b1, hws);
    transpose_cvt<<<dim3(33, 16, NB), 256, 0, stream>>>(W2, W2T, MLP, O2);
    gemm2_mfma<<<dim3(9, 32, NB), 256, 0, stream>>>(hws, W2T, b2, fw, mws);
    gather_masks<<<dim3(NFREQ, BATCH * CCH), 256, 0, stream>>>(mws, (float*)d_out);
}

// Round 3
// 299.851 us; speedup vs baseline: 4.2222x; 1.0705x over previous
//
#include <hip/hip_runtime.h>
#include <math.h>

#define NB    15
#define BWID  129
#define HOP   64
#define NFREQ 1025
#define EMB   128
#define MLP   512
#define OUTC  516
#define O2    1032
#define BATCH 2
#define TLEN  2048
#define REIM  2
#define CCH   2
#define RTOT  (BATCH*NB*TLEN)

typedef _Float16 half8 __attribute__((ext_vector_type(8)));
typedef _Float16 half4 __attribute__((ext_vector_type(4)));
typedef _Float16 half2_ __attribute__((ext_vector_type(2)));
typedef float    floatx4 __attribute__((ext_vector_type(4)));

#define GLOAD_LDS(gsrc, ldst) \
  __builtin_amdgcn_global_load_lds((const __attribute__((address_space(1))) unsigned int*)(gsrc), \
                                   (__attribute__((address_space(3))) unsigned int*)(ldst), 16, 0, 0)

// ---------------- LayerNorm: one wave per row of 128, f16 out ----------------
__global__ __launch_bounds__(256) void ln_kernel(const float* __restrict__ q,
                                                 const float* __restrict__ gamma,
                                                 const float* __restrict__ beta,
                                                 _Float16* __restrict__ qn)
{
    int row  = blockIdx.x * 4 + (threadIdx.x >> 6);
    int lane = threadIdx.x & 63;
    int n    = (row / TLEN) % NB;

    const float2* src = (const float2*)(q + (size_t)row * EMB);
    float2 v = src[lane];
    float s  = v.x + v.y;
    float s2 = v.x * v.x + v.y * v.y;
    #pragma unroll
    for (int off = 1; off < 64; off <<= 1) {
        s  += __shfl_xor(s,  off);
        s2 += __shfl_xor(s2, off);
    }
    float mu   = s * (1.0f / EMB);
    float var  = s2 * (1.0f / EMB) - mu * mu;
    float rstd = rsqrtf(var + 1e-5f);

    float2 g2 = ((const float2*)(gamma + n * EMB))[lane];
    float2 b2 = ((const float2*)(beta  + n * EMB))[lane];
    half2_ o;
    o[0] = (_Float16)((v.x - mu) * rstd * g2.x + b2.x);
    o[1] = (_Float16)((v.y - mu) * rstd * g2.y + b2.y);
    ((half2_*)(qn + (size_t)row * EMB))[lane] = o;
}

// ---------------- transpose + f32->f16: src [R][C] -> dst [C][R], per band ----------------
__global__ __launch_bounds__(256) void transpose_cvt(const float* __restrict__ src,
                                                     _Float16* __restrict__ dst,
                                                     int R, int C)
{
    __shared__ float tile[32][33];
    const int band = blockIdx.z;
    src += (size_t)band * R * C;
    dst += (size_t)band * R * C;
    int tx = threadIdx.x & 31, ty = threadIdx.x >> 5;
    int c0 = blockIdx.x * 32, r0 = blockIdx.y * 32;
    int c = c0 + tx;
    if (c < C) {
        #pragma unroll
        for (int i = 0; i < 4; ++i)
            tile[ty + i * 8][tx] = src[(size_t)(r0 + ty + i * 8) * C + c];
    }
    __syncthreads();
    int r = r0 + tx;
    #pragma unroll
    for (int i = 0; i < 4; ++i) {
        int cw = c0 + ty + i * 8;
        if (cw < C) dst[(size_t)cw * R + r] = (_Float16)tile[tx][ty + i * 8];
    }
}

// ---------------- GEMM1 (MFMA f16): qn(4096x128) @ W1T^T -> tanh -> h f16 ----------------
__global__ __launch_bounds__(256) void gemm1_mfma(const _Float16* __restrict__ qn,
                                                  const _Float16* __restrict__ W1T,
                                                  const float* __restrict__ b1,
                                                  _Float16* __restrict__ h)
{
    __shared__ _Float16 sA[128 * 64];
    __shared__ _Float16 sB[128 * 64];
    const int n   = blockIdx.z;
    const int m0  = blockIdx.y * 128;
    const int n0  = blockIdx.x * 128;
    const int tid = threadIdx.x;
    const int lane = tid & 63;
    const int wave = tid >> 6;
    const int wr = (wave >> 1) * 64;
    const int wc = (wave & 1) * 64;
    const int b = m0 >> 11, t0 = m0 & (TLEN - 1);

    const _Float16* Ab = qn  + ((size_t)(b * NB + n) * TLEN + t0) * EMB;
    const _Float16* Bb = W1T + ((size_t)n * MLP + n0) * EMB;

    floatx4 acc[4][4] = {};

    const int lrow = lane & 15;
    const int q16  = (lane >> 4) << 4;
    const int swz  = (lane & 7) << 4;

    for (int k0 = 0; k0 < EMB; k0 += 64) {
        #pragma unroll
        for (int i = 0; i < 4; ++i) {
            int g = tid + i * 256;
            int r = g >> 3, kb = g & 7;
            int sk = kb ^ (r & 7);
            GLOAD_LDS(Ab + (size_t)r * EMB + k0 + sk * 8, sA + g * 8);
            GLOAD_LDS(Bb + (size_t)r * EMB + k0 + sk * 8, sB + g * 8);
        }
        __syncthreads();
        #pragma unroll
        for (int kk = 0; kk < 2; ++kk) {
            half8 af[4], bf[4];
            #pragma unroll
            for (int m = 0; m < 4; ++m) {
                int r = wr + m * 16 + lrow;
                af[m] = *(const half8*)((const char*)sA + r * 128 + (((kk << 6) | q16) ^ swz));
            }
            #pragma unroll
            for (int nf = 0; nf < 4; ++nf) {
                int r = wc + nf * 16 + lrow;
                bf[nf] = *(const half8*)((const char*)sB + r * 128 + (((kk << 6) | q16) ^ swz));
            }
            #pragma unroll
            for (int m = 0; m < 4; ++m)
                #pragma unroll
                for (int nf = 0; nf < 4; ++nf)
                    acc[m][nf] = __builtin_amdgcn_mfma_f32_16x16x32_f16(af[m], bf[nf], acc[m][nf], 0, 0, 0);
        }
        __syncthreads();
    }

    const int rq = (lane >> 4) * 4;
    _Float16* hb = h + ((size_t)(b * NB + n) * TLEN + t0) * MLP;
    #pragma unroll
    for (int nf = 0; nf < 4; ++nf) {
        int col = n0 + wc + nf * 16 + lrow;
        float bias = b1[n * MLP + col];
        #pragma unroll
        for (int m = 0; m < 4; ++m) {
            int rbase = wr + m * 16 + rq;
            #pragma unroll
            for (int r = 0; r < 4; ++r) {
                float v = tanhf(acc[m][nf][r] + bias);
                hb[(size_t)(rbase + r) * MLP + col] = (_Float16)v;
            }
        }
    }
}

// ---- GEMM2 (MFMA f16): 256-row tile, 512 thr / 8 waves, XCD-swizzled 1-D grid ----
// wave = 64 rows x 32 cols of both a and g halves
__global__ __launch_bounds__(512, 4) void gemm2_mfma(const _Float16* __restrict__ h,
                                                     const _Float16* __restrict__ W2T,
                                                     const float* __restrict__ b2,
                                                     const float* __restrict__ fw,
                                                     _Float16* __restrict__ mws)
{
    __shared__ _Float16 sA[256 * 64];
    __shared__ _Float16 sBa[64 * 64];
    __shared__ _Float16 sBg[64 * 64];

    const int NWG = 9 * 16 * NB;                 // 2160, %8==0 -> bijective
    int flat = blockIdx.x;
    int wg   = (flat & 7) * (NWG / 8) + (flat >> 3);
    int bx   = wg % 9;
    int tmp  = wg / 9;
    int by   = tmp & 15;
    int n    = tmp >> 4;

    const int m0  = by * 256;
    const int n0  = bx * 64;
    const int tid = threadIdx.x;
    const int lane = tid & 63;
    const int wave = tid >> 6;
    const int wm = (wave >> 1) * 64;             // 0,64,128,192
    const int wc = (wave & 1) * 32;              // 0,32
    const int b = m0 >> 11, t0 = m0 & (TLEN - 1);

    const _Float16* Ab  = h   + ((size_t)(b * NB + n) * TLEN + t0) * MLP;
    const _Float16* W2n = W2T + (size_t)n * O2 * MLP;

    floatx4 accA[4][2] = {};
    floatx4 accG[4][2] = {};

    const int lrow = lane & 15;
    const int q16  = (lane >> 4) << 4;
    const int swz  = (lane & 7) << 4;

    for (int k0 = 0; k0 < MLP; k0 += 64) {
        #pragma unroll
        for (int i = 0; i < 4; ++i) {
            int g = tid + i * 512;
            int r = g >> 3, kb = g & 7;
            int sk = kb ^ (r & 7);
            GLOAD_LDS(Ab + (size_t)r * MLP + k0 + sk * 8, sA + g * 8);
        }
        {
            int g = tid;
            int r = g >> 3, kb = g & 7;
            int sk = kb ^ (r & 7);
            int ra = n0 + r;        if (ra > OUTC - 1) ra = OUTC - 1;
            int rg = OUTC + n0 + r; if (rg > O2 - 1)   rg = O2 - 1;
            GLOAD_LDS(W2n + (size_t)ra * MLP + k0 + sk * 8, sBa + g * 8);
            GLOAD_LDS(W2n + (size_t)rg * MLP + k0 + sk * 8, sBg + g * 8);
        }
        __syncthreads();
        #pragma unroll
        for (int kk = 0; kk < 2; ++kk) {
            half8 af[4], ba[2], bg[2];
            #pragma unroll
            for (int m = 0; m < 4; ++m) {
                int r = wm + m * 16 + lrow;
                af[m] = *(const half8*)((const char*)sA + r * 128 + (((kk << 6) | q16) ^ swz));
            }
            #pragma unroll
            for (int nf = 0; nf < 2; ++nf) {
                int r = wc + nf * 16 + lrow;
                ba[nf] = *(const half8*)((const char*)sBa + r * 128 + (((kk << 6) | q16) ^ swz));
                bg[nf] = *(const half8*)((const char*)sBg + r * 128 + (((kk << 6) | q16) ^ swz));
            }
            #pragma unroll
            for (int m = 0; m < 4; ++m)
                #pragma unroll
                for (int nf = 0; nf < 2; ++nf) {
                    accA[m][nf] = __builtin_amdgcn_mfma_f32_16x16x32_f16(af[m], ba[nf], accA[m][nf], 0, 0, 0);
                    accG[m][nf] = __builtin_amdgcn_mfma_f32_16x16x32_f16(af[m], bg[nf], accG[m][nf], 0, 0, 0);
                }
        }
        __syncthreads();
    }

    const int rq = (lane >> 4) * 4;
    const float* b2n = b2 + n * O2;
    #pragma unroll
    for (int nf = 0; nf < 2; ++nf) {
        int c = n0 + wc + nf * 16 + lrow;
        bool valid = c < OUTC;
        int cl = valid ? c : OUTC - 1;
        float biasA = b2n[cl];
        float biasG = b2n[OUTC + cl];
        int rem = cl % 258;
        float w = fw[n * BWID + (rem >> 1)];
        _Float16* mb = mws + ((size_t)((b * NB + n) * OUTC + cl)) * TLEN + t0;
        #pragma unroll
        for (int m = 0; m < 4; ++m) {
            int tb = wm + m * 16 + rq;
            half4 vals;
            #pragma unroll
            for (int r = 0; r < 4; ++r) {
                float a = accA[m][nf][r] + biasA;
                float g = accG[m][nf][r] + biasG;
                vals[r] = (_Float16)(a * w / (1.0f + expf(-g)));
            }
            if (valid) *(half4*)(mb + tb) = vals;
        }
    }
}

// ---------------- gather: vectorized, 8 t-values per thread ----------------
__global__ __launch_bounds__(256) void gather_masks(const _Float16* __restrict__ mws,
                                                    float* __restrict__ out)
{
    const int f  = blockIdx.x;
    const int bc = blockIdx.y;                   // b*2 + cc
    const int b  = bc >> 1, cc = bc & 1;
    int nlo = (f >= 129) ? ((f - 65) >> 6) : 0;
    int nhi = f >> 6; if (nhi > 14) nhi = 14;
    const int t0 = threadIdx.x * 8;

    float a[8] = {0,0,0,0,0,0,0,0};
    float g[8] = {0,0,0,0,0,0,0,0};
    for (int nn = nlo; nn <= nhi; ++nn) {
        int bw = f - (nn << 6);
        int cbase = cc * 258 + (bw << 1);
        const _Float16* p = mws + ((size_t)((b * NB + nn) * OUTC + cbase)) * TLEN + t0;
        half8 va = *(const half8*)p;
        half8 vg = *(const half8*)(p + TLEN);
        #pragma unroll
        for (int j = 0; j < 8; ++j) { a[j] += (float)va[j]; g[j] += (float)vg[j]; }
    }
    float* ob = out + (((size_t)bc * NFREQ + f) * TLEN + t0) * REIM;
    #pragma unroll
    for (int j = 0; j < 4; ++j) {
        float4 v = make_float4(a[2*j], g[2*j], a[2*j+1], g[2*j+1]);
        *(float4*)(ob + j * 4) = v;
    }
}

extern "C" void kernel_launch(void* const* d_in, const int* in_sizes, int n_in,
                              void* d_out, int out_size, void* d_ws, size_t ws_size,
                              hipStream_t stream) {
    const float* q     = (const float*)d_in[0];
    const float* gamma = (const float*)d_in[1];
    const float* beta  = (const float*)d_in[2];
    const float* W1    = (const float*)d_in[3];
    const float* b1    = (const float*)d_in[4];
    const float* W2    = (const float*)d_in[5];
    const float* b2    = (const float*)d_in[6];
    const float* fw    = (const float*)d_in[7];

    _Float16* hws  = (_Float16*)d_ws;
    _Float16* mws  = hws + (size_t)RTOT * MLP;
    _Float16* qnws = mws + (size_t)BATCH * NB * OUTC * TLEN;
    _Float16* W1T  = qnws + (size_t)RTOT * EMB;
    _Float16* W2T  = qnws;                       // alias (qn dead after gemm1)

    ln_kernel<<<RTOT / 4, 256, 0, stream>>>(q, gamma, beta, qnws);
    transpose_cvt<<<dim3(16, 4, NB), 256, 0, stream>>>(W1, W1T, EMB, MLP);
    gemm1_mfma<<<dim3(4, 32, NB), 256, 0, stream>>>(qnws, W1T, b1, hws);
    transpose_cvt<<<dim3(33, 16, NB), 256, 0, stream>>>(W2, W2T, MLP, O2);
    gemm2_mfma<<<9 * 16 * NB, 512, 0, stream>>>(hws, W2T, b2, fw, mws);
    gather_masks<<<dim3(NFREQ, BATCH * CCH), 256, 0, stream>>>(mws, (float*)d_out);
}